// Round 1
// 735.614 us; speedup vs baseline: 1.2891x; 1.2891x over previous
//
#include <hip/hip_runtime.h>

#define D 64
#define EPS 1e-12f

typedef unsigned short u16;

__device__ __forceinline__ float bf2f(u16 u) {
    return __uint_as_float(((unsigned)u) << 16);
}
// round-to-nearest-even f32 -> bf16 (finite values)
__device__ __forceinline__ u16 f2bf(float f) {
    unsigned u = __float_as_uint(f);
    u += 0x7fffu + ((u >> 16) & 1u);
    return (u16)(u >> 16);
}
__device__ __forceinline__ float loadf(const void* p, size_t i, int bf) {
    return bf ? bf2f(((const u16*)p)[i]) : ((const float*)p)[i];
}

#define FMA4(acc, s, v)                       \
    do {                                      \
        acc.x = fmaf((s), (v).x, acc.x);      \
        acc.y = fmaf((s), (v).y, acc.y);      \
        acc.z = fmaf((s), (v).z, acc.z);      \
        acc.w = fmaf((s), (v).w, acc.w);      \
    } while (0)

// Detect input dtype: bf16 N(0,1) data never has exponent >= 0xC0; f32 data
// read as u16 halves triggers constantly. flag=1 -> bf16, flag=0 -> f32.
__global__ __launch_bounds__(64) void detect_kernel(const u16* __restrict__ x,
                                                    int* __restrict__ flag) {
    int lane = threadIdx.x;
    int bad = 0;
    for (int i = 0; i < 64; ++i) {
        u16 u = x[lane * 64 + i];
        int e = (u >> 7) & 0xFF;
        if (e >= 0xC0) bad = 1;
    }
    unsigned long long b = __ballot(bad);
    if (lane == 0) *flag = (b == 0ull) ? 1 : 0;
}

// ---- CSR build (once per launch; shared by both layers) ----

__global__ __launch_bounds__(256) void zero_kernel(int* __restrict__ counts, int N) {
    int i = blockIdx.x * blockDim.x + threadIdx.x;
    if (i < N) counts[i] = 0;
}

__global__ __launch_bounds__(256) void hist_kernel(const int* __restrict__ dst,
                                                   int* __restrict__ counts, int E) {
    int e = blockIdx.x * blockDim.x + threadIdx.x;
    if (e < E) atomicAdd(&counts[dst[e]], 1);
}

// scan1: per-block partial sums over 1024-element chunks
__global__ __launch_bounds__(256) void scan1_kernel(const int* __restrict__ counts,
                                                    int* __restrict__ partials, int N) {
    int b = blockIdx.x, t = threadIdx.x;
    int base = b * 1024 + t * 4;
    int s = 0;
#pragma unroll
    for (int i = 0; i < 4; ++i) {
        int idx = base + i;
        if (idx < N) s += counts[idx];
    }
    s += __shfl_xor(s, 32); s += __shfl_xor(s, 16); s += __shfl_xor(s, 8);
    s += __shfl_xor(s, 4);  s += __shfl_xor(s, 2);  s += __shfl_xor(s, 1);
    __shared__ int wt[4];
    if ((t & 63) == 0) wt[t >> 6] = s;
    __syncthreads();
    if (t == 0) partials[b] = wt[0] + wt[1] + wt[2] + wt[3];
}

// scan2: exclusive scan of block partials (NP ~ 98), single wave
__global__ __launch_bounds__(64) void scan2_kernel(int* __restrict__ partials, int NP) {
    int l = threadIdx.x;
    int total = 0;
    for (int base = 0; base < NP; base += 64) {
        int v = (base + l < NP) ? partials[base + l] : 0;
        int orig = v;
        for (int d = 1; d < 64; d <<= 1) {
            int u = __shfl_up(v, d);
            if (l >= d) v += u;
        }
        int excl = v - orig + total;
        if (base + l < NP) partials[base + l] = excl;
        total += __shfl(v, 63);
    }
}

// scan3: per-element exclusive offsets; also init fill cursors
__global__ __launch_bounds__(256) void scan3_kernel(const int* __restrict__ counts,
                                                    const int* __restrict__ partials,
                                                    int* __restrict__ offsets,
                                                    int* __restrict__ cursor, int N) {
    int b = blockIdx.x, t = threadIdx.x;
    int base = b * 1024 + t * 4;
    int v[4];
    int s = 0;
#pragma unroll
    for (int i = 0; i < 4; ++i) {
        int idx = base + i;
        v[i] = (idx < N) ? counts[idx] : 0;
        s += v[i];
    }
    int li = t & 63, w = t >> 6;
    int inc = s;
    for (int d = 1; d < 64; d <<= 1) {
        int u = __shfl_up(inc, d);
        if (li >= d) inc += u;
    }
    __shared__ int wt[4];
    if (li == 63) wt[w] = inc;
    __syncthreads();
    int woff = 0;
    for (int i = 0; i < w; ++i) woff += wt[i];
    int run = partials[b] + woff + (inc - s);
#pragma unroll
    for (int i = 0; i < 4; ++i) {
        int idx = base + i;
        if (idx < N) {
            offsets[idx] = run;
            cursor[idx] = run;
            run += v[i];
        }
    }
}

__global__ __launch_bounds__(256) void fill_kernel(const int* __restrict__ src,
                                                   const int* __restrict__ dst,
                                                   int* __restrict__ cursor,
                                                   int* __restrict__ sorted_src, int E) {
    int e = blockIdx.x * blockDim.x + threadIdx.x;
    if (e >= E) return;
    int p = atomicAdd(&cursor[dst[e]], 1);
    sorted_src[p] = src[e];
}

// ---- per-layer kernels ----

// Kernel A: per-node L2 norm; store norm and 1/max(norm,eps). No agg write.
__global__ __launch_bounds__(256) void norm_init_kernel(
    const void* __restrict__ xin, float* __restrict__ nx, float* __restrict__ rnx,
    int N, const int* __restrict__ flagp)
{
    const int bf = *flagp;
    int node = (int)((blockIdx.x * blockDim.x + threadIdx.x) >> 6);
    int lane = threadIdx.x & 63;
    if (node >= N) return;
    float v = loadf(xin, (size_t)node * D + lane, bf);
    float s = v * v;
    s += __shfl_xor(s, 32); s += __shfl_xor(s, 16); s += __shfl_xor(s, 8);
    s += __shfl_xor(s, 4);  s += __shfl_xor(s, 2);  s += __shfl_xor(s, 1);
    if (lane == 0) {
        float n = sqrtf(s);
        nx[node] = n;
        rnx[node] = 1.0f / fmaxf(n, EPS);
    }
}

// Kernel B (replaces scatter): pull-mode aggregation via CSR.
// One wave per node, lane = feature. agg[node] = xn[node] + sum_{e in} xn[src].
// xn recomputed as x * rnx (bit-identical to the old scatter's value).
__global__ __launch_bounds__(256) void gather_kernel(
    const int* __restrict__ offsets, const int* __restrict__ counts,
    const int* __restrict__ sorted_src,
    const void* __restrict__ xin, const float* __restrict__ rnx,
    float* __restrict__ agg, int N, const int* __restrict__ flagp)
{
    const int bf = *flagp;
    int node = (int)((blockIdx.x * blockDim.x + threadIdx.x) >> 6);
    int lane = threadIdx.x & 63;
    if (node >= N) return;

    float acc = loadf(xin, (size_t)node * D + lane, bf) * rnx[node];  // self term

    int start = offsets[node];
    int deg = counts[node];
    int i = 0;
    while (i < deg) {
        int cnt = min(deg - i, 64);
        int id = (lane < cnt) ? sorted_src[start + i + lane] : 0;
        for (int j = 0; j < cnt; ++j) {
            int s = __shfl(id, j);
            acc = fmaf(loadf(xin, (size_t)s * D + lane, bf), rnx[s], acc);
        }
        i += cnt;
    }
    agg[(size_t)node * D + lane] = acc;
}

// Kernel C: msg-norm + two 64x64 GEMMs + final l2norm (+optional relu).
// Block = 256 threads = 4 waves; each wave handles 4 nodes/group, 4 groups.
// Lane = sub*16 + cg; lane computes out cols [cg*4 .. cg*4+3] of node (base+sub).
__global__ __launch_bounds__(256) void epilogue_kernel(
    const float* __restrict__ agg, const float* __restrict__ nx,
    const void* __restrict__ xin,
    const void* __restrict__ wl, const void* __restrict__ bl,
    const void* __restrict__ wr, const void* __restrict__ scale_p,
    void* __restrict__ out, int N, const int* __restrict__ flagp, int relu)
{
    __shared__ float lds_wl[D * D];   // transposed: lds_wl[k*64+j] = Wl[j][k]
    __shared__ float lds_wr[D * D];
    __shared__ float lds_bl[D];
    __shared__ float msgbuf[4][4 * 68];  // [wave][sub*68 + k], pad 68
    __shared__ float xrbuf[4][4 * 68];

    const int bf = *flagp;
    const int t = threadIdx.x;
    for (int idx = t; idx < D * D; idx += 256) {
        int j = idx >> 6, k = idx & 63;
        lds_wl[k * D + j] = loadf(wl, idx, bf);
        lds_wr[k * D + j] = loadf(wr, idx, bf);
    }
    if (t < D) lds_bl[t] = loadf(bl, t, bf);
    __syncthreads();

    const float scl = loadf(scale_p, 0, bf);
    const int w = t >> 6, lane = t & 63;
    const int sub = lane >> 4, cg = lane & 15;
    float* mrow = &msgbuf[w][sub * 68];
    float* xrow = &xrbuf[w][sub * 68];

    for (int g = 0; g < 4; ++g) {
        int node = blockIdx.x * 64 + (w * 4 + g) * 4 + sub;
        bool valid = node < N;
        int nc = valid ? node : N - 1;

        // msg = l2norm(agg) * ||x|| * scale
        float4 v4 = ((const float4*)(agg + (size_t)nc * D))[cg];
        float s = v4.x * v4.x + v4.y * v4.y + v4.z * v4.z + v4.w * v4.w;
        s += __shfl_xor(s, 1); s += __shfl_xor(s, 2);
        s += __shfl_xor(s, 4); s += __shfl_xor(s, 8);
        float minv = scl * nx[nc] / fmaxf(sqrtf(s), EPS);

        float4 x4;
        if (bf) {
            ushort4 u = ((const ushort4*)((const u16*)xin + (size_t)nc * D))[cg];
            x4 = make_float4(bf2f(u.x), bf2f(u.y), bf2f(u.z), bf2f(u.w));
        } else {
            x4 = ((const float4*)((const float*)xin + (size_t)nc * D))[cg];
        }

        // wave-local LDS exchange (producer/consumer same wave, in-order LDS)
        *((float4*)(mrow + cg * 4)) =
            make_float4(v4.x * minv, v4.y * minv, v4.z * minv, v4.w * minv);
        *((float4*)(xrow + cg * 4)) = x4;

        float4 acc = ((const float4*)lds_bl)[cg];
#pragma unroll
        for (int k4 = 0; k4 < 16; ++k4) {
            float4 m4  = *((const float4*)(mrow + k4 * 4));
            float4 xr4 = *((const float4*)(xrow + k4 * 4));
            const float* wlp = lds_wl + (k4 * 4) * D + cg * 4;
            const float* wrp = lds_wr + (k4 * 4) * D + cg * 4;
            float4 a;
            a = *((const float4*)(wlp + 0 * D)); FMA4(acc, m4.x, a);
            a = *((const float4*)(wlp + 1 * D)); FMA4(acc, m4.y, a);
            a = *((const float4*)(wlp + 2 * D)); FMA4(acc, m4.z, a);
            a = *((const float4*)(wlp + 3 * D)); FMA4(acc, m4.w, a);
            a = *((const float4*)(wrp + 0 * D)); FMA4(acc, xr4.x, a);
            a = *((const float4*)(wrp + 1 * D)); FMA4(acc, xr4.y, a);
            a = *((const float4*)(wrp + 2 * D)); FMA4(acc, xr4.z, a);
            a = *((const float4*)(wrp + 3 * D)); FMA4(acc, xr4.w, a);
        }

        float s2 = acc.x * acc.x + acc.y * acc.y + acc.z * acc.z + acc.w * acc.w;
        s2 += __shfl_xor(s2, 1); s2 += __shfl_xor(s2, 2);
        s2 += __shfl_xor(s2, 4); s2 += __shfl_xor(s2, 8);
        float inv = 1.0f / fmaxf(sqrtf(s2), EPS);
        float4 r = make_float4(acc.x * inv, acc.y * inv, acc.z * inv, acc.w * inv);
        if (relu) {
            r.x = fmaxf(r.x, 0.f); r.y = fmaxf(r.y, 0.f);
            r.z = fmaxf(r.z, 0.f); r.w = fmaxf(r.w, 0.f);
        }
        if (valid) {
            if (bf) {
                ushort4 o = make_ushort4(f2bf(r.x), f2bf(r.y), f2bf(r.z), f2bf(r.w));
                ((ushort4*)((u16*)out + (size_t)node * D))[cg] = o;
            } else {
                ((float4*)((float*)out + (size_t)node * D))[cg] = r;
            }
        }
    }
}

extern "C" void kernel_launch(void* const* d_in, const int* in_sizes, int n_in,
                              void* d_out, int out_size, void* d_ws, size_t ws_size,
                              hipStream_t stream)
{
    const void* x   = d_in[0];
    const void* Wl0 = d_in[1];
    const void* bl0 = d_in[2];
    const void* Wr0 = d_in[3];
    const void* sc0 = d_in[4];
    const void* Wl1 = d_in[5];
    const void* bl1 = d_in[6];
    const void* Wr1 = d_in[7];
    const void* sc1 = d_in[8];
    const int* ei   = (const int*)d_in[9];

    const int N = in_sizes[0] / D;
    const int E = in_sizes[9] / 2;
    const int* src = ei;
    const int* dst = ei + E;

    const int NP = (N + 1023) / 1024;  // scan partials

    // workspace (~32.5 MB):
    //   agg f32 (N*D) | nx f32 (N) | rnx f32 (N) | flag int |
    //   counts int (N) | offsets int (N) | cursor int (N) |
    //   sorted_src int (E) | partials int (NP)
    float* agg       = (float*)d_ws;
    float* nx        = agg + (size_t)N * D;
    float* rnx       = nx + N;
    int* flag        = (int*)(rnx + N);
    int* counts      = flag + 1;
    int* offsets     = counts + N;
    int* cursor      = offsets + N;
    int* sorted_src  = cursor + N;
    int* partials    = sorted_src + E;

    // inter-layer h lives in d_out (layer-1 epilogue reads only its own row
    // of h before overwriting it; all cross-node h reads happen earlier).
    void* h = d_out;

    dim3 blk(256);
    int gridN  = (N + 255) / 256;   // 1 thread/node
    int gridE  = (E + 255) / 256;   // 1 thread/edge
    int gridA  = (N + 3) / 4;       // 1 wave/node
    int gridC  = (N + 63) / 64;     // epilogue

    detect_kernel<<<1, 64, 0, stream>>>((const u16*)x, flag);

    // ---- CSR build (edge structure shared by both layers) ----
    zero_kernel<<<gridN, blk, 0, stream>>>(counts, N);
    hist_kernel<<<gridE, blk, 0, stream>>>(dst, counts, E);
    scan1_kernel<<<NP, blk, 0, stream>>>(counts, partials, N);
    scan2_kernel<<<1, 64, 0, stream>>>(partials, NP);
    scan3_kernel<<<NP, blk, 0, stream>>>(counts, partials, offsets, cursor, N);
    fill_kernel<<<gridE, blk, 0, stream>>>(src, dst, cursor, sorted_src, E);

    // ---- layer 0 (input x, output h -> d_out, relu) ----
    norm_init_kernel<<<gridA, blk, 0, stream>>>(x, nx, rnx, N, flag);
    gather_kernel<<<gridA, blk, 0, stream>>>(offsets, counts, sorted_src, x, rnx,
                                             agg, N, flag);
    epilogue_kernel<<<gridC, blk, 0, stream>>>(agg, nx, x, Wl0, bl0, Wr0, sc0,
                                               h, N, flag, 1);

    // ---- layer 1 (input h = d_out, output d_out, no relu) ----
    norm_init_kernel<<<gridA, blk, 0, stream>>>(h, nx, rnx, N, flag);
    gather_kernel<<<gridA, blk, 0, stream>>>(offsets, counts, sorted_src, h, rnx,
                                             agg, N, flag);
    epilogue_kernel<<<gridC, blk, 0, stream>>>(agg, nx, h, Wl1, bl1, Wr1, sc1,
                                               d_out, N, flag, 0);
}

// Round 2
// 474.212 us; speedup vs baseline: 1.9998x; 1.5512x over previous
//
#include <hip/hip_runtime.h>

#define D 64
#define EPS 1e-12f
#define WPITCH 68   // LDS row pitch in floats: 68*4B=272B, 16B-aligned, breaks pow2 banks

typedef unsigned short u16;

__device__ __forceinline__ float bf2f(u16 u) {
    return __uint_as_float(((unsigned)u) << 16);
}
// round-to-nearest-even f32 -> bf16 (finite values)
__device__ __forceinline__ u16 f2bf(float f) {
    unsigned u = __float_as_uint(f);
    u += 0x7fffu + ((u >> 16) & 1u);
    return (u16)(u >> 16);
}
__device__ __forceinline__ float loadf(const void* p, size_t i, int bf) {
    return bf ? bf2f(((const u16*)p)[i]) : ((const float*)p)[i];
}

#define FMA4(acc, s, v)                       \
    do {                                      \
        acc.x = fmaf((s), (v).x, acc.x);      \
        acc.y = fmaf((s), (v).y, acc.y);      \
        acc.z = fmaf((s), (v).z, acc.z);      \
        acc.w = fmaf((s), (v).w, acc.w);      \
    } while (0)

// Detect input dtype: bf16 N(0,1) data never has exponent >= 0xC0; f32 data
// read as u16 halves triggers constantly. flag=1 -> bf16, flag=0 -> f32.
__global__ __launch_bounds__(64) void detect_kernel(const u16* __restrict__ x,
                                                    int* __restrict__ flag) {
    int lane = threadIdx.x;
    int bad = 0;
    for (int i = 0; i < 64; ++i) {
        u16 u = x[lane * 64 + i];
        int e = (u >> 7) & 0xFF;
        if (e >= 0xC0) bad = 1;
    }
    unsigned long long b = __ballot(bad);
    if (lane == 0) *flag = (b == 0ull) ? 1 : 0;
}

// ---- CSR build (once per launch; shared by both layers) ----

__global__ __launch_bounds__(256) void zero_kernel(int* __restrict__ counts, int N) {
    int i = blockIdx.x * blockDim.x + threadIdx.x;
    if (i < N) counts[i] = 0;
}

__global__ __launch_bounds__(256) void hist_kernel(const int* __restrict__ dst,
                                                   int* __restrict__ counts, int E) {
    int e = blockIdx.x * blockDim.x + threadIdx.x;
    if (e < E) atomicAdd(&counts[dst[e]], 1);
}

// scan1: per-block partial sums over 1024-element chunks
__global__ __launch_bounds__(256) void scan1_kernel(const int* __restrict__ counts,
                                                    int* __restrict__ partials, int N) {
    int b = blockIdx.x, t = threadIdx.x;
    int base = b * 1024 + t * 4;
    int s = 0;
#pragma unroll
    for (int i = 0; i < 4; ++i) {
        int idx = base + i;
        if (idx < N) s += counts[idx];
    }
    s += __shfl_xor(s, 32); s += __shfl_xor(s, 16); s += __shfl_xor(s, 8);
    s += __shfl_xor(s, 4);  s += __shfl_xor(s, 2);  s += __shfl_xor(s, 1);
    __shared__ int wt[4];
    if ((t & 63) == 0) wt[t >> 6] = s;
    __syncthreads();
    if (t == 0) partials[b] = wt[0] + wt[1] + wt[2] + wt[3];
}

// scan2: exclusive scan of block partials (NP ~ 98), single wave
__global__ __launch_bounds__(64) void scan2_kernel(int* __restrict__ partials, int NP) {
    int l = threadIdx.x;
    int total = 0;
    for (int base = 0; base < NP; base += 64) {
        int v = (base + l < NP) ? partials[base + l] : 0;
        int orig = v;
        for (int d = 1; d < 64; d <<= 1) {
            int u = __shfl_up(v, d);
            if (l >= d) v += u;
        }
        int excl = v - orig + total;
        if (base + l < NP) partials[base + l] = excl;
        total += __shfl(v, 63);
    }
}

// scan3: per-element exclusive offsets; also init fill cursors
__global__ __launch_bounds__(256) void scan3_kernel(const int* __restrict__ counts,
                                                    const int* __restrict__ partials,
                                                    int* __restrict__ offsets,
                                                    int* __restrict__ cursor, int N) {
    int b = blockIdx.x, t = threadIdx.x;
    int base = b * 1024 + t * 4;
    int v[4];
    int s = 0;
#pragma unroll
    for (int i = 0; i < 4; ++i) {
        int idx = base + i;
        v[i] = (idx < N) ? counts[idx] : 0;
        s += v[i];
    }
    int li = t & 63, w = t >> 6;
    int inc = s;
    for (int d = 1; d < 64; d <<= 1) {
        int u = __shfl_up(inc, d);
        if (li >= d) inc += u;
    }
    __shared__ int wt[4];
    if (li == 63) wt[w] = inc;
    __syncthreads();
    int woff = 0;
    for (int i = 0; i < w; ++i) woff += wt[i];
    int run = partials[b] + woff + (inc - s);
#pragma unroll
    for (int i = 0; i < 4; ++i) {
        int idx = base + i;
        if (idx < N) {
            offsets[idx] = run;
            cursor[idx] = run;
            run += v[i];
        }
    }
}

__global__ __launch_bounds__(256) void fill_kernel(const int* __restrict__ src,
                                                   const int* __restrict__ dst,
                                                   int* __restrict__ cursor,
                                                   int* __restrict__ sorted_src, int E) {
    int e = blockIdx.x * blockDim.x + threadIdx.x;
    if (e >= E) return;
    int p = atomicAdd(&cursor[dst[e]], 1);
    sorted_src[p] = src[e];
}

// ---- per-layer kernels ----

// Kernel A: per-node L2 norm; store norm and 1/max(norm,eps).
__global__ __launch_bounds__(256) void norm_init_kernel(
    const void* __restrict__ xin, float* __restrict__ nx, float* __restrict__ rnx,
    int N, const int* __restrict__ flagp)
{
    const int bf = *flagp;
    int node = (int)((blockIdx.x * blockDim.x + threadIdx.x) >> 6);
    int lane = threadIdx.x & 63;
    if (node >= N) return;
    float v = loadf(xin, (size_t)node * D + lane, bf);
    float s = v * v;
    s += __shfl_xor(s, 32); s += __shfl_xor(s, 16); s += __shfl_xor(s, 8);
    s += __shfl_xor(s, 4);  s += __shfl_xor(s, 2);  s += __shfl_xor(s, 1);
    if (lane == 0) {
        float n = sqrtf(s);
        nx[node] = n;
        rnx[node] = 1.0f / fmaxf(n, EPS);
    }
}

// Kernel B: pull-mode aggregation via CSR, one wave per node, lane = feature.
// Batched 8-wide (then 4-wide) so 8 row-loads + 8 rnx loads are in flight;
// the old scalar loop serialized one ~400cy load per edge.
__global__ __launch_bounds__(256) void gather_kernel(
    const int* __restrict__ offsets, const int* __restrict__ counts,
    const int* __restrict__ sorted_src,
    const void* __restrict__ xin, const float* __restrict__ rnx,
    float* __restrict__ agg, int N, const int* __restrict__ flagp)
{
    const int bf = *flagp;
    int node = (int)((blockIdx.x * blockDim.x + threadIdx.x) >> 6);
    int lane = threadIdx.x & 63;
    if (node >= N) return;

    float acc = loadf(xin, (size_t)node * D + lane, bf) * rnx[node];  // self term

    int start = offsets[node];
    int deg = counts[node];
    for (int i = 0; i < deg; i += 64) {
        int cnt = min(deg - i, 64);
        int id = (lane < cnt) ? sorted_src[start + i + lane] : 0;
        int j = 0;
        for (; j + 8 <= cnt; j += 8) {
            float v[8], wv[8];
#pragma unroll
            for (int jj = 0; jj < 8; ++jj) {
                int s = __shfl(id, j + jj);
                wv[jj] = rnx[s];
                v[jj] = loadf(xin, (size_t)s * D + lane, bf);
            }
#pragma unroll
            for (int jj = 0; jj < 8; ++jj) acc = fmaf(v[jj], wv[jj], acc);
        }
        if (j + 4 <= cnt) {
            float v[4], wv[4];
#pragma unroll
            for (int jj = 0; jj < 4; ++jj) {
                int s = __shfl(id, j + jj);
                wv[jj] = rnx[s];
                v[jj] = loadf(xin, (size_t)s * D + lane, bf);
            }
#pragma unroll
            for (int jj = 0; jj < 4; ++jj) acc = fmaf(v[jj], wv[jj], acc);
            j += 4;
        }
        for (; j < cnt; ++j) {
            int s = __shfl(id, j);
            acc = fmaf(loadf(xin, (size_t)s * D + lane, bf), rnx[s], acc);
        }
    }
    agg[(size_t)node * D + lane] = acc;
}

// Kernel C v2: msg-norm + two 64x64 GEMVs + final l2norm (+optional relu).
// Register blocking: lane = (sub, cg); each lane computes 4 nodes x 4 cols.
// Wave = 16 nodes/tile, block = 4 waves = 64 nodes.
// LDS reads/node drop 40 -> ~12 (weights amortized over 4 nodes/lane);
// x operand streamed from global (L1/L2-hot) instead of LDS.
// KSTEP(kk,comp): one k-row of both weight matrices against 4 nodes.
#define KSTEP(kk, comp)                                                     \
    {                                                                       \
        float4 a = *((const float4*)(wlp + (kk) * WPITCH));                 \
        float4 b = *((const float4*)(wrp + (kk) * WPITCH));                 \
        FMA4(acc[0], m[0].comp, a); FMA4(acc[0], xf[0].comp, b);            \
        FMA4(acc[1], m[1].comp, a); FMA4(acc[1], xf[1].comp, b);            \
        FMA4(acc[2], m[2].comp, a); FMA4(acc[2], xf[2].comp, b);            \
        FMA4(acc[3], m[3].comp, a); FMA4(acc[3], xf[3].comp, b);            \
    }

__global__ __launch_bounds__(256) void epilogue_kernel(
    const float* __restrict__ agg, const float* __restrict__ nx,
    const void* __restrict__ xin,
    const void* __restrict__ wl, const void* __restrict__ bl,
    const void* __restrict__ wr, const void* __restrict__ scale_p,
    void* __restrict__ out, int N, const int* __restrict__ flagp, int relu)
{
    __shared__ float lds_wl[D * WPITCH];   // [k*WPITCH + j] = Wl[j][k]
    __shared__ float lds_wr[D * WPITCH];
    __shared__ float lds_bl[D];
    __shared__ float msgbuf[4][16 * WPITCH];  // [wave][row*WPITCH + k]

    const int bf = *flagp;
    const int t = threadIdx.x;
    // staging: coalesced global read; LDS write stride WPITCH=68 floats ->
    // bank (4k+j)%32, 8-way (was 64-way at pitch 64). 32 instrs/block.
    for (int idx = t; idx < D * D; idx += 256) {
        int j = idx >> 6, k = idx & 63;
        lds_wl[k * WPITCH + j] = loadf(wl, idx, bf);
        lds_wr[k * WPITCH + j] = loadf(wr, idx, bf);
    }
    if (t < D) lds_bl[t] = loadf(bl, t, bf);
    __syncthreads();

    const float scl = loadf(scale_p, 0, bf);
    const int w = t >> 6, lane = t & 63;
    const int sub = lane >> 4, cg = lane & 15;

    const int node0 = blockIdx.x * 64 + w * 16 + sub * 4;
    int n[4];
    bool valid[4];
    float4 a4[4];
    float nxv[4];
#pragma unroll
    for (int r = 0; r < 4; ++r) {
        int nn = node0 + r;
        valid[r] = nn < N;
        n[r] = valid[r] ? nn : N - 1;
        a4[r] = ((const float4*)(agg + (size_t)n[r] * D))[cg];
        nxv[r] = nx[n[r]];
    }

    float* mrow = msgbuf[w];
#pragma unroll
    for (int r = 0; r < 4; ++r) {
        float4 v4 = a4[r];
        float s = v4.x * v4.x + v4.y * v4.y + v4.z * v4.z + v4.w * v4.w;
        s += __shfl_xor(s, 1); s += __shfl_xor(s, 2);
        s += __shfl_xor(s, 4); s += __shfl_xor(s, 8);
        float minv = scl * nxv[r] / fmaxf(sqrtf(s), EPS);
        *((float4*)(mrow + (sub * 4 + r) * WPITCH + cg * 4)) =
            make_float4(v4.x * minv, v4.y * minv, v4.z * minv, v4.w * minv);
    }
    // no barrier: producer/consumer lanes are in the same wave (in-order LDS)

    float4 acc[4];
    {
        float4 b4 = ((const float4*)lds_bl)[cg];
#pragma unroll
        for (int r = 0; r < 4; ++r) acc[r] = b4;
    }

    const float* wlbase = lds_wl + cg * 4;
    const float* wrbase = lds_wr + cg * 4;

    if (bf) {
#pragma unroll
        for (int k4 = 0; k4 < 16; ++k4) {
            float4 m[4], xf[4];
#pragma unroll
            for (int r = 0; r < 4; ++r) {
                m[r] = *((const float4*)(mrow + (sub * 4 + r) * WPITCH + k4 * 4));
                ushort4 xu = ((const ushort4*)((const u16*)xin + (size_t)n[r] * D))[k4];
                xf[r] = make_float4(bf2f(xu.x), bf2f(xu.y), bf2f(xu.z), bf2f(xu.w));
            }
            const float* wlp = wlbase + (k4 * 4) * WPITCH;
            const float* wrp = wrbase + (k4 * 4) * WPITCH;
            KSTEP(0, x) KSTEP(1, y) KSTEP(2, z) KSTEP(3, w)
        }
    } else {
#pragma unroll
        for (int k4 = 0; k4 < 16; ++k4) {
            float4 m[4], xf[4];
#pragma unroll
            for (int r = 0; r < 4; ++r) {
                m[r] = *((const float4*)(mrow + (sub * 4 + r) * WPITCH + k4 * 4));
                xf[r] = ((const float4*)((const float*)xin + (size_t)n[r] * D))[k4];
            }
            const float* wlp = wlbase + (k4 * 4) * WPITCH;
            const float* wrp = wrbase + (k4 * 4) * WPITCH;
            KSTEP(0, x) KSTEP(1, y) KSTEP(2, z) KSTEP(3, w)
        }
    }

#pragma unroll
    for (int r = 0; r < 4; ++r) {
        float4 v = acc[r];
        float s2 = v.x * v.x + v.y * v.y + v.z * v.z + v.w * v.w;
        s2 += __shfl_xor(s2, 1); s2 += __shfl_xor(s2, 2);
        s2 += __shfl_xor(s2, 4); s2 += __shfl_xor(s2, 8);
        float inv = 1.0f / fmaxf(sqrtf(s2), EPS);
        float4 rv = make_float4(v.x * inv, v.y * inv, v.z * inv, v.w * inv);
        if (relu) {
            rv.x = fmaxf(rv.x, 0.f); rv.y = fmaxf(rv.y, 0.f);
            rv.z = fmaxf(rv.z, 0.f); rv.w = fmaxf(rv.w, 0.f);
        }
        if (valid[r]) {
            if (bf) {
                ushort4 o = make_ushort4(f2bf(rv.x), f2bf(rv.y), f2bf(rv.z), f2bf(rv.w));
                ((ushort4*)((u16*)out + (size_t)n[r] * D))[cg] = o;
            } else {
                ((float4*)((float*)out + (size_t)n[r] * D))[cg] = rv;
            }
        }
    }
}

extern "C" void kernel_launch(void* const* d_in, const int* in_sizes, int n_in,
                              void* d_out, int out_size, void* d_ws, size_t ws_size,
                              hipStream_t stream)
{
    const void* x   = d_in[0];
    const void* Wl0 = d_in[1];
    const void* bl0 = d_in[2];
    const void* Wr0 = d_in[3];
    const void* sc0 = d_in[4];
    const void* Wl1 = d_in[5];
    const void* bl1 = d_in[6];
    const void* Wr1 = d_in[7];
    const void* sc1 = d_in[8];
    const int* ei   = (const int*)d_in[9];

    const int N = in_sizes[0] / D;
    const int E = in_sizes[9] / 2;
    const int* src = ei;
    const int* dst = ei + E;

    const int NP = (N + 1023) / 1024;  // scan partials

    // workspace (~32.5 MB):
    //   agg f32 (N*D) | nx f32 (N) | rnx f32 (N) | flag int |
    //   counts int (N) | offsets int (N) | cursor int (N) |
    //   sorted_src int (E) | partials int (NP)
    float* agg       = (float*)d_ws;
    float* nx        = agg + (size_t)N * D;
    float* rnx       = nx + N;
    int* flag        = (int*)(rnx + N);
    int* counts      = flag + 1;
    int* offsets     = counts + N;
    int* cursor      = offsets + N;
    int* sorted_src  = cursor + N;
    int* partials    = sorted_src + E;

    // inter-layer h lives in d_out (layer-1 epilogue reads only its own rows
    // of h before overwriting them; all cross-node h reads happen earlier).
    void* h = d_out;

    dim3 blk(256);
    int gridN  = (N + 255) / 256;   // 1 thread/node
    int gridE  = (E + 255) / 256;   // 1 thread/edge
    int gridA  = (N + 3) / 4;       // 1 wave/node
    int gridC  = (N + 63) / 64;     // epilogue: 64 nodes/block

    detect_kernel<<<1, 64, 0, stream>>>((const u16*)x, flag);

    // ---- CSR build (edge structure shared by both layers) ----
    zero_kernel<<<gridN, blk, 0, stream>>>(counts, N);
    hist_kernel<<<gridE, blk, 0, stream>>>(dst, counts, E);
    scan1_kernel<<<NP, blk, 0, stream>>>(counts, partials, N);
    scan2_kernel<<<1, 64, 0, stream>>>(partials, NP);
    scan3_kernel<<<NP, blk, 0, stream>>>(counts, partials, offsets, cursor, N);
    fill_kernel<<<gridE, blk, 0, stream>>>(src, dst, cursor, sorted_src, E);

    // ---- layer 0 (input x, output h -> d_out, relu) ----
    norm_init_kernel<<<gridA, blk, 0, stream>>>(x, nx, rnx, N, flag);
    gather_kernel<<<gridA, blk, 0, stream>>>(offsets, counts, sorted_src, x, rnx,
                                             agg, N, flag);
    epilogue_kernel<<<gridC, blk, 0, stream>>>(agg, nx, x, Wl0, bl0, Wr0, sc0,
                                               h, N, flag, 1);

    // ---- layer 1 (input h = d_out, output d_out, no relu) ----
    norm_init_kernel<<<gridA, blk, 0, stream>>>(h, nx, rnx, N, flag);
    gather_kernel<<<gridA, blk, 0, stream>>>(offsets, counts, sorted_src, h, rnx,
                                             agg, N, flag);
    epilogue_kernel<<<gridC, blk, 0, stream>>>(agg, nx, h, Wl1, bl1, Wr1, sc1,
                                               d_out, N, flag, 0);
}